// Round 11
// baseline (125.276 us; speedup 1.0000x reference)
//
#include <hip/hip_runtime.h>
#include <hip/hip_bf16.h>

typedef unsigned short u16;
typedef unsigned int u32;
typedef __bf16 bf16x8_t __attribute__((ext_vector_type(8)));
typedef float f32x4_t __attribute__((ext_vector_type(4)));
typedef float f32x16 __attribute__((ext_vector_type(16)));

constexpr int Bb = 4;
constexpr int Tt = 4096;
constexpr int Dd = 64;
constexpr float QSCALE = 0.18033688011112042f; // 0.125 * log2(e), folded into q

__device__ __forceinline__ u16 f2bf(float f) { // RNE
  unsigned int u = __builtin_bit_cast(unsigned int, f);
  return (u16)((u + 0x7fffu + ((u >> 16) & 1u)) >> 16);
}
__device__ __forceinline__ u32 pk2(float a, float b) { // RNE pack
  return (u32)f2bf(a) | ((u32)f2bf(b) << 16);
}
__device__ __forceinline__ u32 pkt(float a, float b) { // truncation pack (3 inst)
  const u32 ua = __builtin_bit_cast(u32, a);
  const u32 ub = __builtin_bit_cast(u32, b);
  return (ua >> 16) | (ub & 0xFFFF0000u);
}
__device__ __forceinline__ bf16x8_t ld16(const u16* p) {
  int4 v = *(const int4*)p;
  return __builtin_bit_cast(bf16x8_t, v);
}
__device__ __forceinline__ f32x4_t mfma16(bf16x8_t a, bf16x8_t b, f32x4_t c) {
  return __builtin_amdgcn_mfma_f32_16x16x32_bf16(a, b, c, 0, 0, 0);
}
__device__ __forceinline__ f32x16 mfma32(bf16x8_t a, bf16x8_t b, f32x16 c) {
  return __builtin_amdgcn_mfma_f32_32x32x16_bf16(a, b, c, 0, 0, 0);
}

// ---------------- proj v5 (R10, verified): 16-wave, parallel k/q/v wave-groups ----------------
__global__ __launch_bounds__(1024) void HeadV1_proj(
    const float* __restrict__ x, const float* __restrict__ Wk,
    const float* __restrict__ Wq, const float* __restrict__ Wv,
    u16* __restrict__ qS, u16* __restrict__ kS, u16* __restrict__ vS)
{
  __shared__ u16 xl[64][72];       //  9216 B
  __shared__ u16 Wl[3][64][72];    // 27648 B
  __shared__ u16 yl[3][64][72];    // 27648 B (total 64512 B)

  const int t = threadIdx.x;
  const int w = t >> 6, lane = t & 63, l15 = lane & 15, quad = lane >> 4;
  const int blk = blockIdx.x;
  const int r0 = blk * 64;
  const int b  = blk >> 6;
  const int kt = blk & 63;
  const long tilebase = ((long)(b * 64 + kt)) * 4096;

  { // staging: 1024 threads x 1 float4 per source tile
    const float* srcs[4] = {x + (long)r0 * 64, Wk, Wq, Wv};
    u16* dstl[4] = {&xl[0][0], &Wl[0][0][0], &Wl[1][0][0], &Wl[2][0][0]};
    const int row = t >> 4, c4 = t & 15;
    #pragma unroll
    for (int mm = 0; mm < 4; mm++) {
      float4 v = ((const float4*)(srcs[mm] + row * 64))[c4];
      uint2 pk;
      pk.x = pk2(v.x, v.y);
      pk.y = pk2(v.z, v.w);
      *(uint2*)(dstl[mm] + row * 72 + c4 * 4) = pk;
    }
  }
  __syncthreads();

  const int mg = w >> 2;       // wave group: 0=k 1=q 2=v 3=idle
  const int wl = w & 3;        // wave-in-group
  if (mg < 3) {
    bf16x8_t xf[2];
    #pragma unroll
    for (int kh = 0; kh < 2; kh++)
      xf[kh] = ld16(&xl[wl * 16 + l15][kh * 32 + quad * 8]);

    float vals[4][4];
    #pragma unroll
    for (int g = 0; g < 4; g++) {
      f32x4_t acc = {0.f, 0.f, 0.f, 0.f};
      #pragma unroll
      for (int kh = 0; kh < 2; kh++) {
        bf16x8_t wf = ld16(&Wl[mg][g * 16 + l15][kh * 32 + quad * 8]);
        acc = mfma16(xf[kh], wf, acc);
      }
      #pragma unroll
      for (int r = 0; r < 4; r++)
        vals[g][r] = (mg == 1) ? acc[r] * QSCALE : acc[r];
    }
    #pragma unroll
    for (int g = 0; g < 4; g++)
      #pragma unroll
      for (int r = 0; r < 4; r++)
        yl[mg][wl * 16 + quad * 4 + r][g * 16 + l15] = f2bf(vals[g][r]);
  }
  __syncthreads();

  if (mg < 3) {
    u16* dsts[3];
    dsts[0] = kS + tilebase; dsts[1] = qS + tilebase; dsts[2] = vS + tilebase;
    if (mg < 2) {
      #pragma unroll
      for (int kk = 0; kk < 2; kk++) {
        bf16x8_t f = ld16(&yl[mg][wl * 16 + l15][kk * 32 + quad * 8]);
        *(int4*)(dsts[mg] + (wl * 2 + kk) * 512 + lane * 8) = __builtin_bit_cast(int4, f);
      }
    } else {
      #pragma unroll
      for (int kk = 0; kk < 2; kk++) {
        u16 tmp[8];
        #pragma unroll
        for (int jj = 0; jj < 8; jj++)
          tmp[jj] = yl[2][kk * 32 + quad * 8 + jj][wl * 16 + l15];
        *(int4*)(dsts[2] + (kk * 4 + wl) * 512 + lane * 8) = *(const int4*)tmp;
      }
    }
  }
}

// ---------------- flash v17: q-64 per wave, Q in LDS (K/V traffic 266 -> 133 MB) ----------------
// Block (b,i) = one q-64 tile; ALL 16 waves share it (Q staged once in LDS, 16 KB; fragments
// re-read per visit -> persistent regs = O only). Wave w strides kv tiles w, w+16, ... of
// nk = i+1. Per visit: kf[4] vs TWO q column groups (A: q0-31, B: q32-63) -> 8 QK mfma32,
// two packs (v15's verified scalar truncated-L), 8 PV mfma32. Diagonal: (A,h2=1) fully
// masked -> skipped; mask predicate slot>q31 at (A,h2=0) and (B,h2=1). XCD-locked decode (R7).
__global__ __launch_bounds__(1024) void HeadV1_flash(
    const u16* __restrict__ qS, const u16* __restrict__ kS,
    const u16* __restrict__ vS, float* __restrict__ outg)
{
  __shared__ __align__(16) char smem[93184];
  u16*  qlds            = (u16*)smem;                            // 16384 B (main loop)
  float (*chk)[16][66]  = (float (*)[16][66])smem;               // 67584 B (overlays qlds)
  float (*stg)[32][68]  = (float (*)[32][68])(smem + 67584);     // 17408 B
  float (*lst)[2][2][32]= (float (*)[2][2][32])(smem + 84992);   //  8192 B [w][g][lhb][q]

  const int t    = threadIdx.x;
  const int w    = t >> 6;        // 0..15
  const int lane = t & 63;
  const int l15  = lane & 15;
  const int lhb  = lane >> 5;
  const int l4   = (lane >> 4) & 1;
  const int q31  = lane & 31;

  const int xcd = blockIdx.x & 7;
  const int b   = xcd >> 1;                              // batch locked to XCD pair
  const int i   = ((blockIdx.x >> 3) << 1) | (xcd & 1);  // q-64 tile 0..63 (bijective)
  const int nk  = i + 1;                                 // kv tiles (last = diagonal)
  const long base = (long)b * Tt * Dd;

  { // stage q-64 tile to LDS once (1024 thr x 16 B = 16 KB)
    const u16* qt_ = qS + ((long)(b * 64 + i)) * 4096;
    *(int4*)(qlds + t * 8) = *(const int4*)(qt_ + t * 8);
  }
  __syncthreads();

  const f32x16 z16 = {0.f,0.f,0.f,0.f,0.f,0.f,0.f,0.f,0.f,0.f,0.f,0.f,0.f,0.f,0.f,0.f};
  f32x16 OA0 = z16, OA1 = z16, OB0 = z16, OB1 = z16;
  float LpA = 0.f, LpB = 0.f;

  const u16* kb = kS + ((long)(b * 64)) * 4096;
  const u16* vb = vS + ((long)(b * 64)) * 4096;

  auto tr = [](float e) {
    return __builtin_bit_cast(float, __builtin_bit_cast(u32, e) & 0xFFFF0000u);
  };
  // exp2 + truncation pack of one 8-reg half of S; accumulates truncated sum into Lp
  auto packhalf = [&](const f32x16& S, int ksl, float& Lp) -> bf16x8_t {
    const float e0 = __builtin_amdgcn_exp2f(S[8 * ksl + 0]);
    const float e1 = __builtin_amdgcn_exp2f(S[8 * ksl + 1]);
    const float e2 = __builtin_amdgcn_exp2f(S[8 * ksl + 2]);
    const float e3 = __builtin_amdgcn_exp2f(S[8 * ksl + 3]);
    const float e4 = __builtin_amdgcn_exp2f(S[8 * ksl + 4]);
    const float e5 = __builtin_amdgcn_exp2f(S[8 * ksl + 5]);
    const float e6 = __builtin_amdgcn_exp2f(S[8 * ksl + 6]);
    const float e7 = __builtin_amdgcn_exp2f(S[8 * ksl + 7]);
    Lp += ((tr(e0) + tr(e1)) + (tr(e2) + tr(e3))) + ((tr(e4) + tr(e5)) + (tr(e6) + tr(e7)));
    const u32 b0 = pkt(e0, e1), b1 = pkt(e2, e3), b2 = pkt(e4, e5), b3 = pkt(e6, e7);
    // partner exchange: lo needs hi's b0,b1 (words 2,3); hi needs lo's b2,b3 (words 0,1)
    const u32 x02 = (u32)__shfl_xor((int)(lhb ? b0 : b2), 32);
    const u32 x13 = (u32)__shfl_xor((int)(lhb ? b1 : b3), 32);
    uint4 bw;
    bw.x = lhb ? x02 : b0;
    bw.y = lhb ? x13 : b1;
    bw.z = lhb ? b2 : x02;
    bw.w = lhb ? b3 : x13;
    return __builtin_bit_cast(bf16x8_t, bw);
  };

  for (int kt = w; kt < nk; kt += 16) {
    const bool last = (kt == nk - 1);
    const u16* ktile = kb + (long)kt * 4096;
    const u16* vtile = vb + (long)kt * 4096;

    #pragma unroll
    for (int h2 = 0; h2 < 2; h2++) {
      const bool doA = !(last && h2 == 1);   // (A, h2=1) on diagonal: fully masked

      bf16x8_t kf[4];
      #pragma unroll
      for (int dsl = 0; dsl < 4; dsl++)
        kf[dsl] = ld16(ktile + ((h2 * 2 + l4) * 2 + (dsl >> 1)) * 512
                             + (((dsl * 2 + lhb) & 3) * 16 + l15) * 8);

      bf16x8_t BfA0, BfA1;
      if (doA) {  // group A: q cols 0-31 (col-group offset 0)
        f32x16 S = z16;
        #pragma unroll
        for (int dsl = 0; dsl < 4; dsl++)
          S = mfma32(kf[dsl], ld16(qlds + (l4 * 2 + (dsl >> 1)) * 512
                                        + (((dsl * 2 + lhb) & 3) * 16 + l15) * 8), S);
        if (last) {   // h2==0 diagonal: mask slot > q31
          #pragma unroll
          for (int r = 0; r < 16; r++)
            if (4 * lhb + (r & 3) + 8 * (r >> 2) > q31) S[r] = -1e30f;
        }
        BfA0 = packhalf(S, 0, LpA);
        BfA1 = packhalf(S, 1, LpA);
      }

      // group B: q cols 32-63 (col-group offset 2)
      f32x16 S = z16;
      #pragma unroll
      for (int dsl = 0; dsl < 4; dsl++)
        S = mfma32(kf[dsl], ld16(qlds + ((2 + l4) * 2 + (dsl >> 1)) * 512
                                      + (((dsl * 2 + lhb) & 3) * 16 + l15) * 8), S);
      if (last && h2 == 1) {   // diagonal for B
        #pragma unroll
        for (int r = 0; r < 16; r++)
          if (4 * lhb + (r & 3) + 8 * (r >> 2) > q31) S[r] = -1e30f;
      }

      bf16x8_t vf[2][2];
      #pragma unroll
      for (int ksl = 0; ksl < 2; ksl++)
        #pragma unroll
        for (int dh = 0; dh < 2; dh++)
          vf[ksl][dh] = ld16(vtile + (h2 * 4 + dh * 2 + l4) * 512
                                   + ((ksl * 2 + lhb) * 16 + l15) * 8);

      const bf16x8_t BfB0 = packhalf(S, 0, LpB);   // covers vf load latency
      const bf16x8_t BfB1 = packhalf(S, 1, LpB);

      __builtin_amdgcn_s_setprio(1);
      if (doA) {
        OA0 = mfma32(vf[0][0], BfA0, OA0);  OA1 = mfma32(vf[0][1], BfA0, OA1);
        OA0 = mfma32(vf[1][0], BfA1, OA0);  OA1 = mfma32(vf[1][1], BfA1, OA1);
      }
      OB0 = mfma32(vf[0][0], BfB0, OB0);  OB1 = mfma32(vf[0][1], BfB0, OB1);
      OB0 = mfma32(vf[1][0], BfB1, OB0);  OB1 = mfma32(vf[1][1], BfB1, OB1);
      __builtin_amdgcn_s_setprio(0);
    }
  }

  // ---- 16-wave merge (idle waves contribute zeros) ----
  lst[w][0][lhb][q31] = LpA;   // lhb partners hold complementary kv slots of the column
  lst[w][1][lhb][q31] = LpB;
  __syncthreads();  // qlds dead past here; chk overlays it

  #pragma unroll
  for (int rr = 0; rr < 4; rr++) {   // d_global = rr*16 + dloc
    #pragma unroll
    for (int rs = 0; rs < 8; rs++) {
      const int dloc = (rs & 3) + 8 * (rs >> 2) + 4 * lhb;
      const float vA = (rr >> 1) ? ((rr & 1) ? OA1[8 + rs] : OA1[rs])
                                 : ((rr & 1) ? OA0[8 + rs] : OA0[rs]);
      const float vB = (rr >> 1) ? ((rr & 1) ? OB1[8 + rs] : OB1[rs])
                                 : ((rr & 1) ? OB0[8 + rs] : OB0[rs]);
      chk[w][dloc][q31]      = vA;
      chk[w][dloc][32 + q31] = vB;
    }
    __syncthreads();
    {
      const int d2 = t >> 6, q = t & 63;   // 1024 thr = 16 d x 64 q
      float s = 0.f;
      #pragma unroll
      for (int w2 = 0; w2 < 16; w2++) s += chk[w2][d2][q];
      stg[q >> 5][q & 31][rr * 16 + d2] = s;
    }
    __syncthreads();
  }

  { // normalize + coalesced fp32 write: 64 q x 64 d (1024 thr x 16 B)
    const int g = t >> 9, tt = t & 511;
    const int q = tt >> 4, dg = tt & 15;
    float L = 0.f;
    #pragma unroll
    for (int w2 = 0; w2 < 16; w2++) L += lst[w2][g][0][q] + lst[w2][g][1][q];
    const float invL = 1.0f / L;
    float4 v = *(const float4*)&stg[g][q][dg * 4];
    v.x *= invL; v.y *= invL; v.z *= invL; v.w *= invL;
    *(float4*)(outg + base + (long)(i * 64 + g * 32 + q) * 64 + dg * 4) = v;
  }
}

extern "C" void kernel_launch(void* const* d_in, const int* in_sizes, int n_in,
                              void* d_out, int out_size, void* d_ws, size_t ws_size,
                              hipStream_t stream) {
  (void)in_sizes; (void)n_in; (void)out_size; (void)ws_size;
  const float* x  = (const float*)d_in[0];
  const float* Wk = (const float*)d_in[1];
  const float* Wq = (const float*)d_in[2];
  const float* Wv = (const float*)d_in[3];
  float* out = (float*)d_out;
  // workspace: qS 2MB | kS 2MB | vS 2MB (all in MFMA-fragment order)
  u16* qw  = (u16*)d_ws;
  u16* kw  = qw + (size_t)Bb * Tt * Dd;
  u16* vw  = kw + (size_t)Bb * Tt * Dd;

  HeadV1_proj<<<(Bb * Tt) / 64, 1024, 0, stream>>>(x, Wk, Wq, Wv, qw, kw, vw);
  HeadV1_flash<<<256, 1024, 0, stream>>>(qw, kw, vw, out);
}

// Round 12
// 121.942 us; speedup vs baseline: 1.0273x; 1.0273x over previous
//
#include <hip/hip_runtime.h>
#include <hip/hip_bf16.h>

typedef unsigned short u16;
typedef unsigned int u32;
typedef __bf16 bf16x8_t __attribute__((ext_vector_type(8)));
typedef float f32x4_t __attribute__((ext_vector_type(4)));
typedef float f32x16 __attribute__((ext_vector_type(16)));

constexpr int Bb = 4;
constexpr int Tt = 4096;
constexpr int Dd = 64;
constexpr float QSCALE = 0.18033688011112042f; // 0.125 * log2(e), folded into q

__device__ __forceinline__ u16 f2bf(float f) { // RNE
  unsigned int u = __builtin_bit_cast(unsigned int, f);
  return (u16)((u + 0x7fffu + ((u >> 16) & 1u)) >> 16);
}
__device__ __forceinline__ u32 pk2(float a, float b) { // RNE pack
  return (u32)f2bf(a) | ((u32)f2bf(b) << 16);
}
__device__ __forceinline__ u32 pkt(float a, float b) { // truncation pack (3 inst)
  const u32 ua = __builtin_bit_cast(u32, a);
  const u32 ub = __builtin_bit_cast(u32, b);
  return (ua >> 16) | (ub & 0xFFFF0000u);
}
__device__ __forceinline__ float trf(float e) { // truncate to bf16 value (as PV consumes)
  return __builtin_bit_cast(float, __builtin_bit_cast(u32, e) & 0xFFFF0000u);
}
__device__ __forceinline__ bf16x8_t ld16(const u16* p) {
  int4 v = *(const int4*)p;
  return __builtin_bit_cast(bf16x8_t, v);
}
__device__ __forceinline__ f32x4_t mfma16(bf16x8_t a, bf16x8_t b, f32x4_t c) {
  return __builtin_amdgcn_mfma_f32_16x16x32_bf16(a, b, c, 0, 0, 0);
}
__device__ __forceinline__ f32x16 mfma32(bf16x8_t a, bf16x8_t b, f32x16 c) {
  return __builtin_amdgcn_mfma_f32_32x32x16_bf16(a, b, c, 0, 0, 0);
}

// exp2 + truncation pack of 8 S-values (literal-indexed: no runtime vector subscripts, rule #20);
// accumulates truncated sum into Lp; returns the PV B-fragment after the lane+-32 partner swap.
__device__ __forceinline__ bf16x8_t pack8(int lhb, float& Lp,
    float s0, float s1, float s2, float s3, float s4, float s5, float s6, float s7) {
  const float e0 = __builtin_amdgcn_exp2f(s0);
  const float e1 = __builtin_amdgcn_exp2f(s1);
  const float e2 = __builtin_amdgcn_exp2f(s2);
  const float e3 = __builtin_amdgcn_exp2f(s3);
  const float e4 = __builtin_amdgcn_exp2f(s4);
  const float e5 = __builtin_amdgcn_exp2f(s5);
  const float e6 = __builtin_amdgcn_exp2f(s6);
  const float e7 = __builtin_amdgcn_exp2f(s7);
  Lp += ((trf(e0) + trf(e1)) + (trf(e2) + trf(e3)))
      + ((trf(e4) + trf(e5)) + (trf(e6) + trf(e7)));
  const u32 b0 = pkt(e0, e1), b1 = pkt(e2, e3), b2 = pkt(e4, e5), b3 = pkt(e6, e7);
  // partner exchange: lo needs hi's b0,b1 (words 2,3); hi needs lo's b2,b3 (words 0,1)
  const u32 x02 = (u32)__shfl_xor((int)(lhb ? b0 : b2), 32);
  const u32 x13 = (u32)__shfl_xor((int)(lhb ? b1 : b3), 32);
  uint4 bw;
  bw.x = lhb ? x02 : b0;
  bw.y = lhb ? x13 : b1;
  bw.z = lhb ? b2 : x02;
  bw.w = lhb ? b3 : x13;
  return __builtin_bit_cast(bf16x8_t, bw);
}

// ---------------- proj v5 (R10, verified): 16-wave, parallel k/q/v wave-groups ----------------
__global__ __launch_bounds__(1024) void HeadV1_proj(
    const float* __restrict__ x, const float* __restrict__ Wk,
    const float* __restrict__ Wq, const float* __restrict__ Wv,
    u16* __restrict__ qS, u16* __restrict__ kS, u16* __restrict__ vS)
{
  __shared__ u16 xl[64][72];       //  9216 B
  __shared__ u16 Wl[3][64][72];    // 27648 B
  __shared__ u16 yl[3][64][72];    // 27648 B (total 64512 B)

  const int t = threadIdx.x;
  const int w = t >> 6, lane = t & 63, l15 = lane & 15, quad = lane >> 4;
  const int blk = blockIdx.x;
  const int r0 = blk * 64;
  const int b  = blk >> 6;
  const int kt = blk & 63;
  const long tilebase = ((long)(b * 64 + kt)) * 4096;

  { // staging: 1024 threads x 1 float4 per source tile
    const float* srcs[4] = {x + (long)r0 * 64, Wk, Wq, Wv};
    u16* dstl[4] = {&xl[0][0], &Wl[0][0][0], &Wl[1][0][0], &Wl[2][0][0]};
    const int row = t >> 4, c4 = t & 15;
    #pragma unroll
    for (int mm = 0; mm < 4; mm++) {
      float4 v = ((const float4*)(srcs[mm] + row * 64))[c4];
      uint2 pk;
      pk.x = pk2(v.x, v.y);
      pk.y = pk2(v.z, v.w);
      *(uint2*)(dstl[mm] + row * 72 + c4 * 4) = pk;
    }
  }
  __syncthreads();

  const int mg = w >> 2;       // wave group: 0=k 1=q 2=v 3=idle
  const int wl = w & 3;        // wave-in-group
  if (mg < 3) {
    bf16x8_t xf[2];
    #pragma unroll
    for (int kh = 0; kh < 2; kh++)
      xf[kh] = ld16(&xl[wl * 16 + l15][kh * 32 + quad * 8]);

    float vals[4][4];
    #pragma unroll
    for (int g = 0; g < 4; g++) {
      f32x4_t acc = {0.f, 0.f, 0.f, 0.f};
      #pragma unroll
      for (int kh = 0; kh < 2; kh++) {
        bf16x8_t wf = ld16(&Wl[mg][g * 16 + l15][kh * 32 + quad * 8]);
        acc = mfma16(xf[kh], wf, acc);
      }
      #pragma unroll
      for (int r = 0; r < 4; r++)
        vals[g][r] = (mg == 1) ? acc[r] * QSCALE : acc[r];
    }
    #pragma unroll
    for (int g = 0; g < 4; g++)
      #pragma unroll
      for (int r = 0; r < 4; r++)
        yl[mg][wl * 16 + quad * 4 + r][g * 16 + l15] = f2bf(vals[g][r]);
  }
  __syncthreads();

  if (mg < 3) {
    u16* dsts[3];
    dsts[0] = kS + tilebase; dsts[1] = qS + tilebase; dsts[2] = vS + tilebase;
    if (mg < 2) {
      #pragma unroll
      for (int kk = 0; kk < 2; kk++) {
        bf16x8_t f = ld16(&yl[mg][wl * 16 + l15][kk * 32 + quad * 8]);
        *(int4*)(dsts[mg] + (wl * 2 + kk) * 512 + lane * 8) = __builtin_bit_cast(int4, f);
      }
    } else {
      #pragma unroll
      for (int kk = 0; kk < 2; kk++) {
        u16 tmp[8];
        #pragma unroll
        for (int jj = 0; jj < 8; jj++)
          tmp[jj] = yl[2][kk * 32 + quad * 8 + jj][wl * 16 + l15];
        *(int4*)(dsts[2] + (kk * 4 + wl) * 512 + lane * 8) = *(const int4*)tmp;
      }
    }
  }
}

// ---------------- flash v18: v17 spill-proofed (traffic 266 -> 133 MB, NO scratch) ----------------
// Changes vs v17 (which scratch-spilled: 81 MB WRITE_SIZE):
//  (1) __launch_bounds__(1024, 4): allows the 128-VGPR bin (v17's bare (1024) made the compiler
//      target the 64-VGPR bin and spill ~50 regs to scratch).
//  (2) per-visit, each q column group runs QK->pack->PV TO COMPLETION before the other group
//      starts: A's Bf regs die before B's S is live. Peak ~115 regs < 128.
//  (3) pack8 takes 8 scalars (literal vector subscripts only).
// Math per accumulator identical to v17 (R11 passed correctness).
__global__ __launch_bounds__(1024, 4) void HeadV1_flash(
    const u16* __restrict__ qS, const u16* __restrict__ kS,
    const u16* __restrict__ vS, float* __restrict__ outg)
{
  __shared__ __align__(16) char smem[93184];
  u16*  qlds            = (u16*)smem;                            // 16384 B (main loop)
  float (*chk)[16][66]  = (float (*)[16][66])smem;               // 67584 B (overlays qlds)
  float (*stg)[32][68]  = (float (*)[32][68])(smem + 67584);     // 17408 B
  float (*lst)[2][2][32]= (float (*)[2][2][32])(smem + 84992);   //  8192 B [w][g][lhb][q]

  const int t    = threadIdx.x;
  const int w    = t >> 6;        // 0..15
  const int lane = t & 63;
  const int l15  = lane & 15;
  const int lhb  = lane >> 5;
  const int l4   = (lane >> 4) & 1;
  const int q31  = lane & 31;

  const int xcd = blockIdx.x & 7;
  const int b   = xcd >> 1;                              // batch locked to XCD pair
  const int i   = ((blockIdx.x >> 3) << 1) | (xcd & 1);  // q-64 tile 0..63 (bijective)
  const int nk  = i + 1;                                 // kv tiles (last = diagonal)
  const long base = (long)b * Tt * Dd;

  { // stage q-64 tile to LDS once (1024 thr x 16 B = 16 KB)
    const u16* qt_ = qS + ((long)(b * 64 + i)) * 4096;
    *(int4*)(qlds + t * 8) = *(const int4*)(qt_ + t * 8);
  }
  __syncthreads();

  const f32x16 z16 = {0.f,0.f,0.f,0.f,0.f,0.f,0.f,0.f,0.f,0.f,0.f,0.f,0.f,0.f,0.f,0.f};
  f32x16 OA0 = z16, OA1 = z16, OB0 = z16, OB1 = z16;
  float LpA = 0.f, LpB = 0.f;

  const u16* kb = kS + ((long)(b * 64)) * 4096;
  const u16* vb = vS + ((long)(b * 64)) * 4096;

  for (int kt = w; kt < nk; kt += 16) {
    const bool last = (kt == nk - 1);
    const u16* ktile = kb + (long)kt * 4096;
    const u16* vtile = vb + (long)kt * 4096;

    #pragma unroll
    for (int h2 = 0; h2 < 2; h2++) {
      bf16x8_t kf[4];
      #pragma unroll
      for (int dsl = 0; dsl < 4; dsl++)
        kf[dsl] = ld16(ktile + ((h2 * 2 + l4) * 2 + (dsl >> 1)) * 512
                             + (((dsl * 2 + lhb) & 3) * 16 + l15) * 8);

      // ---- group A: q cols 0-31 (complete before B starts) ----
      if (!(last && h2 == 1)) {   // (A, h2=1) on diagonal: fully masked -> skip
        f32x16 S = z16;
        #pragma unroll
        for (int dsl = 0; dsl < 4; dsl++)
          S = mfma32(kf[dsl], ld16(qlds + (l4 * 2 + (dsl >> 1)) * 512
                                        + (((dsl * 2 + lhb) & 3) * 16 + l15) * 8), S);
        if (last) {   // diagonal at h2==0: mask slot > q31
          #pragma unroll
          for (int r = 0; r < 16; r++)
            if (4 * lhb + (r & 3) + 8 * (r >> 2) > q31) S[r] = -1e30f;
        }
        const bf16x8_t B0 = pack8(lhb, LpA, S[0], S[1], S[2], S[3], S[4], S[5], S[6], S[7]);
        const bf16x8_t B1 = pack8(lhb, LpA, S[8], S[9], S[10], S[11], S[12], S[13], S[14], S[15]);
        bf16x8_t vf[2][2];
        #pragma unroll
        for (int ksl = 0; ksl < 2; ksl++)
          #pragma unroll
          for (int dh = 0; dh < 2; dh++)
            vf[ksl][dh] = ld16(vtile + (h2 * 4 + dh * 2 + l4) * 512
                                     + ((ksl * 2 + lhb) * 16 + l15) * 8);
        __builtin_amdgcn_s_setprio(1);
        OA0 = mfma32(vf[0][0], B0, OA0);  OA1 = mfma32(vf[0][1], B0, OA1);
        OA0 = mfma32(vf[1][0], B1, OA0);  OA1 = mfma32(vf[1][1], B1, OA1);
        __builtin_amdgcn_s_setprio(0);
      }

      // ---- group B: q cols 32-63 ----
      {
        f32x16 S = z16;
        #pragma unroll
        for (int dsl = 0; dsl < 4; dsl++)
          S = mfma32(kf[dsl], ld16(qlds + ((2 + l4) * 2 + (dsl >> 1)) * 512
                                        + (((dsl * 2 + lhb) & 3) * 16 + l15) * 8), S);
        if (last && h2 == 1) {   // diagonal for B
          #pragma unroll
          for (int r = 0; r < 16; r++)
            if (4 * lhb + (r & 3) + 8 * (r >> 2) > q31) S[r] = -1e30f;
        }
        const bf16x8_t B0 = pack8(lhb, LpB, S[0], S[1], S[2], S[3], S[4], S[5], S[6], S[7]);
        const bf16x8_t B1 = pack8(lhb, LpB, S[8], S[9], S[10], S[11], S[12], S[13], S[14], S[15]);
        bf16x8_t vf[2][2];
        #pragma unroll
        for (int ksl = 0; ksl < 2; ksl++)
          #pragma unroll
          for (int dh = 0; dh < 2; dh++)
            vf[ksl][dh] = ld16(vtile + (h2 * 4 + dh * 2 + l4) * 512
                                     + ((ksl * 2 + lhb) * 16 + l15) * 8);
        __builtin_amdgcn_s_setprio(1);
        OB0 = mfma32(vf[0][0], B0, OB0);  OB1 = mfma32(vf[0][1], B0, OB1);
        OB0 = mfma32(vf[1][0], B1, OB0);  OB1 = mfma32(vf[1][1], B1, OB1);
        __builtin_amdgcn_s_setprio(0);
      }
    }
  }

  // ---- 16-wave merge (idle waves contribute zeros) ----
  lst[w][0][lhb][q31] = LpA;   // lhb partners hold complementary kv slots of the column
  lst[w][1][lhb][q31] = LpB;
  __syncthreads();  // qlds dead past here; chk overlays it

  #pragma unroll
  for (int rr = 0; rr < 4; rr++) {   // d_global = rr*16 + dloc
    #pragma unroll
    for (int rs = 0; rs < 8; rs++) {
      const int dloc = (rs & 3) + 8 * (rs >> 2) + 4 * lhb;
      const float vA = (rr >> 1) ? ((rr & 1) ? OA1[8 + rs] : OA1[rs])
                                 : ((rr & 1) ? OA0[8 + rs] : OA0[rs]);
      const float vB = (rr >> 1) ? ((rr & 1) ? OB1[8 + rs] : OB1[rs])
                                 : ((rr & 1) ? OB0[8 + rs] : OB0[rs]);
      chk[w][dloc][q31]      = vA;
      chk[w][dloc][32 + q31] = vB;
    }
    __syncthreads();
    {
      const int d2 = t >> 6, q = t & 63;   // 1024 thr = 16 d x 64 q
      float s = 0.f;
      #pragma unroll
      for (int w2 = 0; w2 < 16; w2++) s += chk[w2][d2][q];
      stg[q >> 5][q & 31][rr * 16 + d2] = s;
    }
    __syncthreads();
  }

  { // normalize + coalesced fp32 write: 64 q x 64 d (1024 thr x 16 B)
    const int g = t >> 9, tt = t & 511;
    const int q = tt >> 4, dg = tt & 15;
    float L = 0.f;
    #pragma unroll
    for (int w2 = 0; w2 < 16; w2++) L += lst[w2][g][0][q] + lst[w2][g][1][q];
    const float invL = 1.0f / L;
    float4 v = *(const float4*)&stg[g][q][dg * 4];
    v.x *= invL; v.y *= invL; v.z *= invL; v.w *= invL;
    *(float4*)(outg + base + (long)(i * 64 + g * 32 + q) * 64 + dg * 4) = v;
  }
}

extern "C" void kernel_launch(void* const* d_in, const int* in_sizes, int n_in,
                              void* d_out, int out_size, void* d_ws, size_t ws_size,
                              hipStream_t stream) {
  (void)in_sizes; (void)n_in; (void)out_size; (void)ws_size;
  const float* x  = (const float*)d_in[0];
  const float* Wk = (const float*)d_in[1];
  const float* Wq = (const float*)d_in[2];
  const float* Wv = (const float*)d_in[3];
  float* out = (float*)d_out;
  // workspace: qS 2MB | kS 2MB | vS 2MB (all in MFMA-fragment order)
  u16* qw  = (u16*)d_ws;
  u16* kw  = qw + (size_t)Bb * Tt * Dd;
  u16* vw  = kw + (size_t)Bb * Tt * Dd;

  HeadV1_proj<<<(Bb * Tt) / 64, 1024, 0, stream>>>(x, Wk, Wq, Wv, qw, kw, vw);
  HeadV1_flash<<<256, 1024, 0, stream>>>(qw, kw, vw, out);
}